// Round 15
// baseline (109.084 us; speedup 1.0000x reference)
//
#include <hip/hip_runtime.h>

#define NPIX 1024
#define CC   512
#define DK   64
#define LOG2E 1.4426950408889634f

typedef __attribute__((ext_vector_type(8)))  short s16x8;
typedef __attribute__((ext_vector_type(8)))  _Float16 f16x8;
typedef __attribute__((ext_vector_type(16))) float f32x16;

union U4 { uint4 u; s16x8 v; };
union U4H { uint4 u; f16x8 v; };

__device__ __forceinline__ ushort f2bf(float f) {
  uint u = __float_as_uint(f);
  uint r = (u + 0x7fffu + ((u >> 16) & 1u)) >> 16;
  return (ushort)r;
}
__device__ __forceinline__ float bf2f(ushort h) { return __uint_as_float(((uint)h) << 16); }
__device__ __forceinline__ ushort f2h(float f) {
  union { _Float16 h; ushort u; } c;
  c.h = (_Float16)f;
  return c.u;
}
__device__ __forceinline__ float h2f(ushort u) {
  union { ushort u; _Float16 h; } c;
  c.u = u;
  return (float)c.h;
}

// single-instruction helpers (r9 VALU trim)
__device__ __forceinline__ uint cvtpk(float a, float b) {
  uint r;
  asm("v_cvt_pk_bf16_f32 %0, %1, %2" : "=v"(r) : "v"(a), "v"(b));
  return r;
}
__device__ __forceinline__ float fmax3(float a, float b, float c) {
  float d;
  asm("v_max3_f32 %0, %1, %2, %3" : "=v"(d) : "v"(a), "v"(b), "v"(c));
  return d;
}
__device__ __forceinline__ float exp2raw(float x) {
  float r;
  asm("v_exp_f32 %0, %1" : "=v"(r) : "v"(x));
  return r;
}

__device__ __forceinline__ f32x16 mfma32(s16x8 a, s16x8 b, f32x16 c) {
  return __builtin_amdgcn_mfma_f32_32x32x16_bf16(a, b, c, 0, 0, 0);
}
__device__ __forceinline__ f32x16 mfma32h(f16x8 a, f16x8 b, f32x16 c) {
  return __builtin_amdgcn_mfma_f32_32x32x16_f16(a, b, c, 0, 0, 0);
}

__device__ __forceinline__ void gl16(const void* g, void* l) {
  __builtin_amdgcn_global_load_lds(
      (const __attribute__((address_space(1))) void*)g,
      (__attribute__((address_space(3))) void*)l, 16, 0, 0);
}

// ---------------------------------------------------------------------------
// pos -> posH/posL[h][n][d]  (f16 hi/lo, d contiguous, 128B rows)
// ---------------------------------------------------------------------------
__global__ void pos_kernel(const float* __restrict__ rel_h,
                           const float* __restrict__ rel_w,
                           ushort* __restrict__ posH, ushort* __restrict__ posL) {
  int t = blockIdx.x * 256 + threadIdx.x;     // 65536 threads
  int g = t & 7;
  int n = (t >> 3) & (NPIX - 1);
  int h = t >> 13;
  int xw = n >> 5, yh = n & 31;
  ushort hbuf[8], lbuf[8];
#pragma unroll
  for (int j = 0; j < 8; ++j) {
    int d = g * 8 + j;
    float v = rel_h[(h * 64 + d) * 32 + yh] + rel_w[(h * 64 + d) * 32 + xw];
    ushort hi = f2h(v);
    hbuf[j] = hi;
    lbuf[j] = f2h(v - h2f(hi));
  }
  size_t base = ((size_t)(h * NPIX + n)) * 64 + g * 8;
  *(uint4*)&posH[base] = *(uint4*)hbuf;
  *(uint4*)&posL[base] = *(uint4*)lbuf;
}

// ---------------------------------------------------------------------------
// W conversion: wq/wk/wv [o][c] fp32 -> Wh/Wl[p][o][c] f16 hi/lo of 64*W
// ---------------------------------------------------------------------------
__global__ __launch_bounds__(256) void cvt_w_kernel(
    const float* __restrict__ wq, const float* __restrict__ wk,
    const float* __restrict__ wv,
    ushort* __restrict__ Wh, ushort* __restrict__ Wl) {
  int lin8 = blockIdx.x * 256 + threadIdx.x;    // 98304 threads, 8 elems each
  int p = lin8 >> 15;
  int o = (lin8 & 32767) >> 6;
  int co = lin8 & 63;
  const float* Wsrc = (p == 0) ? wq : (p == 1) ? wk : wv;
  const float* src = &Wsrc[o * CC + co * 8];
  float4 f0 = *(const float4*)src;
  float4 f1 = *(const float4*)(src + 4);
  float f[8] = {f0.x, f0.y, f0.z, f0.w, f1.x, f1.y, f1.z, f1.w};
  ushort h8[8], l8[8];
#pragma unroll
  for (int j = 0; j < 8; ++j) {
    float sv = f[j] * 64.0f;
    ushort hi = f2h(sv);
    h8[j] = hi;
    l8[j] = f2h(sv - h2f(hi));
  }
  size_t dst = ((size_t)(p * CC + o)) * CC + co * 8;
  *(uint4*)&Wh[dst] = *(uint4*)h8;
  *(uint4*)&Wl[dst] = *(uint4*)l8;
}

// ---------------------------------------------------------------------------
// X transpose+convert: x[b][c][n] fp32 -> Xh[b][n][c] f16 hi only
// ---------------------------------------------------------------------------
__global__ __launch_bounds__(256) void cvt_x_kernel(
    const float* __restrict__ x, ushort* __restrict__ Xh) {
  int t = blockIdx.x * 256 + threadIdx.x;      // 524288 threads
  int nl = t & (NPIX - 1);
  int rest = t >> 10;
  int co = rest & 63;
  int b = rest >> 6;
  ushort h8[8];
#pragma unroll
  for (int j = 0; j < 8; ++j) {
    float v = x[(((size_t)(b * CC + co * 8 + j)) << 10) + nl];
    h8[j] = f2h(v);
  }
  size_t dst = (((size_t)(b * NPIX + nl)) << 9) + co * 8;
  *(uint4*)&Xh[dst] = *(uint4*)h8;
}

// ---------------------------------------------------------------------------
// Projection GEMM via f16 MFMA, 2-product compensation (unchanged from r14).
// ---------------------------------------------------------------------------
__global__ __launch_bounds__(256, 2) void proj_kernel(
    const ushort* __restrict__ Xh, const ushort* __restrict__ Wh,
    const ushort* __restrict__ Wl,
    const float* __restrict__ bq, const float* __restrict__ bk,
    const float* __restrict__ bv,
    ushort* __restrict__ KQh, ushort* __restrict__ KQl,
    ushort* __restrict__ Vb) {
  __shared__ __align__(16) ushort sW[128 * 128];   // 32KB
  __shared__ __align__(16) ushort sX[128 * 64];    // 16KB

  int tid = threadIdx.x;
  int lane = tid & 63;
  int w = tid >> 6;
  int col = lane & 31;
  int half = lane >> 5;
  int srow = lane >> 4;
  int sslot = lane & 15;

  int z = blockIdx.z;
  int b = z / 3, p = z % 3;
  const float* bias = (p == 0) ? bq : (p == 1) ? bk : bv;

  int n0 = blockIdx.x * 128;
  int o0 = blockIdx.y * 128;
  int wo = w >> 1;
  int wn = w & 1;

  f32x16 acc[2][2];
#pragma unroll
  for (int i = 0; i < 2; ++i)
#pragma unroll
    for (int j = 0; j < 2; ++j)
#pragma unroll
      for (int r = 0; r < 16; ++r) acc[i][j][r] = 0.f;

#pragma unroll 1
  for (int c0 = 0; c0 < CC; c0 += 64) {
#pragma unroll
    for (int i = 0; i < 8; ++i) {
      int rbase = (i * 4 + w) * 4;
      int row = rbase + srow;
      int j = sslot ^ (row & 15);
      int jc = j & 7;
      const ushort* src = (j < 8 || p == 2) ? Wh : Wl;
      size_t g = ((size_t)(p * CC + o0 + row)) * CC + c0 + jc * 8;
      gl16(src + g, (char*)sW + rbase * 256);
    }
#pragma unroll
    for (int i = 0; i < 4; ++i) {
      int rbase = i * 32 + w * 8;
      int row = rbase + (lane >> 3);
      int jc = (lane & 7) ^ (row & 7);
      size_t g = ((size_t)(b * NPIX + n0 + row)) * CC + c0 + jc * 8;
      gl16(Xh + g, (char*)sX + rbase * 128);
    }
    __syncthreads();

#pragma unroll
    for (int s = 0; s < 4; ++s) {
      if (p < 2) {
        f16x8 xa[2], wh_[2], wl_[2];
#pragma unroll
        for (int mt = 0; mt < 2; ++mt) {
          int row = wn * 64 + mt * 32 + col;
          int slot = ((s * 2 + half) ^ (row & 7)) << 4;
          xa[mt] = *(const f16x8*)((const char*)sX + row * 128 + slot);
        }
#pragma unroll
        for (int ct = 0; ct < 2; ++ct) {
          int row = wo * 64 + ct * 32 + col;
          int sh = ((s * 2 + half) ^ (row & 15)) << 4;
          int sl = ((8 + s * 2 + half) ^ (row & 15)) << 4;
          wh_[ct] = *(const f16x8*)((const char*)sW + row * 256 + sh);
          wl_[ct] = *(const f16x8*)((const char*)sW + row * 256 + sl);
        }
#pragma unroll
        for (int mt = 0; mt < 2; ++mt)
#pragma unroll
          for (int ct = 0; ct < 2; ++ct) {
            acc[mt][ct] = mfma32h(xa[mt], wh_[ct], acc[mt][ct]);
            acc[mt][ct] = mfma32h(xa[mt], wl_[ct], acc[mt][ct]);
          }
      } else {
        f16x8 wa[2], xb[2];
#pragma unroll
        for (int mt = 0; mt < 2; ++mt) {
          int row = wo * 64 + mt * 32 + col;
          int sh = ((s * 2 + half) ^ (row & 15)) << 4;
          wa[mt] = *(const f16x8*)((const char*)sW + row * 256 + sh);
        }
#pragma unroll
        for (int ct = 0; ct < 2; ++ct) {
          int row = wn * 64 + ct * 32 + col;
          int slot = ((s * 2 + half) ^ (row & 7)) << 4;
          xb[ct] = *(const f16x8*)((const char*)sX + row * 128 + slot);
        }
#pragma unroll
        for (int mt = 0; mt < 2; ++mt)
#pragma unroll
          for (int ct = 0; ct < 2; ++ct)
            acc[mt][ct] = mfma32h(wa[mt], xb[ct], acc[mt][ct]);
      }
    }
    __syncthreads();
  }

  const float INV64 = 0.015625f;
  if (p < 2) {
    float qscale = (p == 0) ? LOG2E : 1.0f;
#pragma unroll
    for (int ct = 0; ct < 2; ++ct) {
      int o = o0 + wo * 64 + ct * 32 + col;
      int bh = b * 8 + (o >> 6);
      int kk = ((p == 0) ? 64 : 0) + (o & 63);
      float bias_v = bias[o];
#pragma unroll
      for (int mt = 0; mt < 2; ++mt) {
        int nbase = n0 + wn * 64 + mt * 32;
#pragma unroll
        for (int r = 0; r < 16; ++r) {
          int n = nbase + (r & 3) + 8 * (r >> 2) + 4 * half;
          float v = (acc[mt][ct][r] * INV64 + bias_v) * qscale;
          ushort hi = f2h(v);
          size_t addr = (((size_t)bh << 10) + n) * 128 + kk;
          KQh[addr] = hi;
          if (p == 0) KQl[addr] = f2h(v - h2f(hi));
        }
      }
    }
  } else {
#pragma unroll
    for (int ct = 0; ct < 2; ++ct) {
      int n = n0 + wn * 64 + ct * 32 + col;
#pragma unroll
      for (int mt = 0; mt < 2; ++mt) {
        int obase = o0 + wo * 64 + mt * 32;
#pragma unroll
        for (int r = 0; r < 16; ++r) {
          int o = obase + (r & 3) + 8 * (r >> 2) + 4 * half;
          int bh = b * 8 + (o >> 6);
          int d = o & 63;
          float v = acc[mt][ct][r] * INV64 + bias[o];
          Vb[(((size_t)(bh * 64 + d)) << 10) + n] = f2bf(v);
        }
      }
    }
  }
}

// ---------------------------------------------------------------------------
// Fused MFMA attention — r15: double-buffered 64-key chunks.
// Per chunk: issue next chunk's gl16 (buffer B) BEFORE computing from A, so
// the barrier's vmcnt drain overlaps the whole compute phase. LDS unchanged
// at 48KB (2 x (16K sKh + 8K sV)). Tree reductions for softmax max/sum.
// ---------------------------------------------------------------------------
__global__ __launch_bounds__(256, 2) void attn_kernel(
    const ushort* __restrict__ KQh, const ushort* __restrict__ KQl,
    const ushort* __restrict__ posH, const ushort* __restrict__ posL,
    const ushort* __restrict__ Vb, float* __restrict__ out) {
  __shared__ __align__(16) ushort sKh[2][64 * 128];   // 16KB each
  __shared__ __align__(16) ushort sV[2][64 * 64];     // 8KB each

  int tid = threadIdx.x;
  int lane = tid & 63;
  int w = tid >> 6;

  int bid = blockIdx.x;
  int wg = (bid & 7) * 64 + (bid >> 3);
  int bh = wg >> 3;
  int qb = wg & 7;
  int h = bh & 7;

  int col = lane & 31;
  int half = lane >> 5;
  int q0 = qb * 128 + w * 32;
  int q = q0 + col;

  // resident B-fragments (f16): [Q(n)*log2e | pos(n)], hi and lo
  uint4 bqh[8], bql[8];
  {
    const ushort* rowQh = KQh + ((size_t)bh * NPIX + q) * 128;
    const ushort* rowQl = KQl + ((size_t)bh * NPIX + q) * 128;
#pragma unroll
    for (int s = 0; s < 4; ++s) {
      int off = 64 + s * 16 + half * 8;
      bqh[s] = *(const uint4*)(rowQh + off);
      bql[s] = *(const uint4*)(rowQl + off);
    }
    const ushort* rowPh = posH + ((size_t)(h * NPIX + q)) * 64;
    const ushort* rowPl = posL + ((size_t)(h * NPIX + q)) * 64;
#pragma unroll
    for (int s = 4; s < 8; ++s) {
      int off = (s - 4) * 16 + half * 8;
      bqh[s] = *(const uint4*)(rowPh + off);
      bql[s] = *(const uint4*)(rowPl + off);
    }
  }

  f32x16 oacc[2];
#pragma unroll
  for (int t = 0; t < 2; ++t)
#pragma unroll
    for (int r = 0; r < 16; ++r) oacc[t][r] = 0.f;
  float m_ = -1e30f, l_ = 0.f;

  int srow = lane >> 4;
  int sslot = lane & 15;

  // ---- stage one 64-key chunk into buffer `buf` ----
#define STAGE(bufi, k0)                                                      \
  {                                                                          \
    _Pragma("unroll")                                                        \
    for (int i = 0; i < 4; ++i) {                                            \
      int row = w * 16 + i * 4 + srow;                                       \
      size_t goff = ((size_t)bh * NPIX + (k0) + row) * 128 +                 \
                    ((sslot ^ (row & 15)) << 3);                             \
      gl16(KQh + goff, (char*)&sKh[bufi][0] + (w * 16 + i * 4) * 256);       \
    }                                                                        \
    _Pragma("unroll")                                                        \
    for (int i = 0; i < 2; ++i) {                                            \
      int d = w * 16 + i * 8 + (lane >> 3);                                  \
      int ks = (lane & 7) ^ (d & 7);                                         \
      size_t goff = ((size_t)(bh * 64 + d)) * NPIX + (k0) + (ks << 3);       \
      gl16(Vb + goff, (char*)&sV[bufi][0] + (w * 16 + i * 8) * 128);         \
    }                                                                        \
  }

  STAGE(0, 0);
  __syncthreads();

#pragma unroll 1
  for (int c = 0; c < 16; ++c) {
    int buf = c & 1;
    if (c < 15) STAGE(buf ^ 1, (c + 1) * 64);

    // ---- S phase: 2 key-tiles x 8 kk-steps x 2 f16 products ----
    f32x16 sa[2];
#pragma unroll
    for (int t = 0; t < 2; ++t)
#pragma unroll
      for (int r = 0; r < 16; ++r) sa[t][r] = 0.f;

    __builtin_amdgcn_s_setprio(1);
#pragma unroll
    for (int s = 0; s < 8; ++s) {
      U4H ubh, ubl;
      ubh.u = bqh[s];
      ubl.u = bql[s];
#pragma unroll
      for (int t = 0; t < 2; ++t) {
        int row = t * 32 + col;
        int slot = ((s * 2 + half) ^ (row & 15)) << 4;
        const f16x8 ah = *(const f16x8*)((const char*)&sKh[buf][0] + row * 256 + slot);
        sa[t] = mfma32h(ah, ubh.v, sa[t]);
        sa[t] = mfma32h(ah, ubl.v, sa[t]);
      }
    }
    __builtin_amdgcn_s_setprio(0);

    // ---- online softmax (exp2 domain), tree max, defer-max rescale ----
    float mxp[4];
#pragma unroll
    for (int j = 0; j < 4; ++j) {
      int ti = j >> 1;
      int b0 = (j & 1) * 8;
      float a = fmax3(sa[ti][b0 + 0], sa[ti][b0 + 1], sa[ti][b0 + 2]);
      float b1 = fmax3(sa[ti][b0 + 3], sa[ti][b0 + 4], sa[ti][b0 + 5]);
      float c1 = fmax3(sa[ti][b0 + 6], sa[ti][b0 + 7], a);
      mxp[j] = fmaxf(b1, c1);
    }
    float mx = fmaxf(fmax3(mxp[0], mxp[1], mxp[2]), mxp[3]);
    mx = fmaxf(mx, __shfl_xor(mx, 32));
    if (!__all(mx - m_ <= 11.54f)) {
      float mn = fmaxf(m_, mx);
      float sc = exp2raw(m_ - mn);
      l_ *= sc;
#pragma unroll
      for (int t = 0; t < 2; ++t)
#pragma unroll
        for (int r = 0; r < 16; ++r) oacc[t][r] *= sc;
      m_ = mn;
    }
#pragma unroll
    for (int t = 0; t < 2; ++t)
#pragma unroll
      for (int r = 0; r < 16; ++r) sa[t][r] = exp2raw(sa[t][r] - m_);
    // tree sum (depth 5)
    float sp[8];
#pragma unroll
    for (int j = 0; j < 8; ++j) {
      int ti = j >> 2;
      int b0 = (j & 3) * 4;
      sp[j] = (sa[ti][b0 + 0] + sa[ti][b0 + 1]) + (sa[ti][b0 + 2] + sa[ti][b0 + 3]);
    }
    float ssum = ((sp[0] + sp[1]) + (sp[2] + sp[3])) + ((sp[4] + sp[5]) + (sp[6] + sp[7]));
    ssum += __shfl_xor(ssum, 32);
    l_ += ssum;

    // ---- PV (bf16), cvt_pk pack ----
#pragma unroll
    for (int t = 0; t < 2; ++t) {
      uint ua[4], ub[4], xa[4], xb[4];
#pragma unroll
      for (int g = 0; g < 4; ++g) {
        ua[g] = cvtpk(sa[t][4 * g + 0], sa[t][4 * g + 1]);
        ub[g] = cvtpk(sa[t][4 * g + 2], sa[t][4 * g + 3]);
      }
#pragma unroll
      for (int g = 0; g < 4; ++g) {
        xa[g] = __shfl_xor(ua[g], 32);
        xb[g] = __shfl_xor(ub[g], 32);
      }
      __builtin_amdgcn_s_setprio(1);
#pragma unroll
      for (int st = 0; st < 2; ++st) {
        int g = st * 2 + half;
        U4 pf;
        if (half == 0) {
          pf.u.x = ua[g]; pf.u.y = ub[g]; pf.u.z = xa[g]; pf.u.w = xb[g];
        } else {
          pf.u.x = xa[g]; pf.u.y = xb[g]; pf.u.z = ua[g]; pf.u.w = ub[g];
        }
#pragma unroll
        for (int dt = 0; dt < 2; ++dt) {
          int d = dt * 32 + col;
          int slot = ((t * 4 + st * 2 + half) ^ (d & 7)) << 4;
          const s16x8 vf = *(const s16x8*)((const char*)&sV[buf][0] + d * 128 + slot);
          oacc[dt] = mfma32(vf, pf.v, oacc[dt]);
        }
      }
      __builtin_amdgcn_s_setprio(0);
    }
    __syncthreads();
  }
#undef STAGE

  float inv = 1.0f / l_;
#pragma unroll
  for (int dt = 0; dt < 2; ++dt)
#pragma unroll
    for (int r = 0; r < 16; ++r) {
      int d = dt * 32 + (r & 3) + 8 * (r >> 2) + 4 * half;
      out[((size_t)(bh * 64 + d) << 10) + q] = oacc[dt][r] * inv;
    }
}

// ---------------------------------------------------------------------------
extern "C" void kernel_launch(void* const* d_in, const int* in_sizes, int n_in,
                              void* d_out, int out_size, void* d_ws, size_t ws_size,
                              hipStream_t stream) {
  const float* x     = (const float*)d_in[0];
  const float* wq    = (const float*)d_in[1];
  const float* bq    = (const float*)d_in[2];
  const float* wk    = (const float*)d_in[3];
  const float* bk    = (const float*)d_in[4];
  const float* wv    = (const float*)d_in[5];
  const float* bv    = (const float*)d_in[6];
  const float* rel_h = (const float*)d_in[7];
  const float* rel_w = (const float*)d_in[8];
  float* out = (float*)d_out;

  // ws (MB): KQh 16 | KQl 16 | Vb 8 | posH 1 | posL 1 | Xh 8 | Wh 1.5 | Wl 1.5
  const size_t MB = 1024 * 1024;
  char* ws = (char*)d_ws;
  ushort* KQh  = (ushort*)(ws);
  ushort* KQl  = (ushort*)(ws + 16 * MB);
  ushort* Vb   = (ushort*)(ws + 32 * MB);
  ushort* posH = (ushort*)(ws + 40 * MB);
  ushort* posL = (ushort*)(ws + 41 * MB);
  ushort* Xh   = (ushort*)(ws + 42 * MB);
  ushort* Wh   = (ushort*)(ws + 50 * MB);
  ushort* Wl   = (ushort*)(ws + 50 * MB + 1572864);

  pos_kernel<<<dim3(256), dim3(256), 0, stream>>>(rel_h, rel_w, posH, posL);
  cvt_w_kernel<<<dim3(384), dim3(256), 0, stream>>>(wq, wk, wv, Wh, Wl);
  cvt_x_kernel<<<dim3(2048), dim3(256), 0, stream>>>(x, Xh);
  proj_kernel<<<dim3(8, 4, 24), dim3(256), 0, stream>>>(
      Xh, Wh, Wl, bq, bk, bv, KQh, KQl, Vb);
  attn_kernel<<<dim3(512), dim3(256), 0, stream>>>(KQh, KQl, posH, posL, Vb, out);
}

// Round 16
// 98.370 us; speedup vs baseline: 1.1089x; 1.1089x over previous
//
#include <hip/hip_runtime.h>

#define NPIX 1024
#define CC   512
#define DK   64
#define LOG2E 1.4426950408889634f

typedef __attribute__((ext_vector_type(8)))  short s16x8;
typedef __attribute__((ext_vector_type(8)))  _Float16 f16x8;
typedef __attribute__((ext_vector_type(16))) float f32x16;

union U4 { uint4 u; s16x8 v; };
union U4H { uint4 u; f16x8 v; };

__device__ __forceinline__ ushort f2bf(float f) {
  uint u = __float_as_uint(f);
  uint r = (u + 0x7fffu + ((u >> 16) & 1u)) >> 16;
  return (ushort)r;
}
__device__ __forceinline__ float bf2f(ushort h) { return __uint_as_float(((uint)h) << 16); }
__device__ __forceinline__ ushort f2h(float f) {
  union { _Float16 h; ushort u; } c;
  c.h = (_Float16)f;
  return c.u;
}
__device__ __forceinline__ float h2f(ushort u) {
  union { ushort u; _Float16 h; } c;
  c.u = u;
  return (float)c.h;
}

// single-instruction helpers (r9 VALU trim)
__device__ __forceinline__ uint cvtpk(float a, float b) {
  uint r;
  asm("v_cvt_pk_bf16_f32 %0, %1, %2" : "=v"(r) : "v"(a), "v"(b));
  return r;
}
__device__ __forceinline__ float fmax3(float a, float b, float c) {
  float d;
  asm("v_max3_f32 %0, %1, %2, %3" : "=v"(d) : "v"(a), "v"(b), "v"(c));
  return d;
}
__device__ __forceinline__ float exp2raw(float x) {
  float r;
  asm("v_exp_f32 %0, %1" : "=v"(r) : "v"(x));
  return r;
}

__device__ __forceinline__ f32x16 mfma32(s16x8 a, s16x8 b, f32x16 c) {
  return __builtin_amdgcn_mfma_f32_32x32x16_bf16(a, b, c, 0, 0, 0);
}
__device__ __forceinline__ f32x16 mfma32h(f16x8 a, f16x8 b, f32x16 c) {
  return __builtin_amdgcn_mfma_f32_32x32x16_f16(a, b, c, 0, 0, 0);
}

__device__ __forceinline__ void gl16(const void* g, void* l) {
  __builtin_amdgcn_global_load_lds(
      (const __attribute__((address_space(1))) void*)g,
      (__attribute__((address_space(3))) void*)l, 16, 0, 0);
}

// ---------------------------------------------------------------------------
// pos -> posH[h][n][d]  (f16 hi only — r16: lo term dropped, see attn)
// ---------------------------------------------------------------------------
__global__ void pos_kernel(const float* __restrict__ rel_h,
                           const float* __restrict__ rel_w,
                           ushort* __restrict__ posH) {
  int t = blockIdx.x * 256 + threadIdx.x;     // 65536 threads
  int g = t & 7;
  int n = (t >> 3) & (NPIX - 1);
  int h = t >> 13;
  int xw = n >> 5, yh = n & 31;
  ushort hbuf[8];
#pragma unroll
  for (int j = 0; j < 8; ++j) {
    int d = g * 8 + j;
    float v = rel_h[(h * 64 + d) * 32 + yh] + rel_w[(h * 64 + d) * 32 + xw];
    hbuf[j] = f2h(v);
  }
  size_t base = ((size_t)(h * NPIX + n)) * 64 + g * 8;
  *(uint4*)&posH[base] = *(uint4*)hbuf;
}

// ---------------------------------------------------------------------------
// W conversion: wq/wk/wv [o][c] fp32 -> Wh/Wl[p][o][c] f16 hi/lo of 64*W
// ---------------------------------------------------------------------------
__global__ __launch_bounds__(256) void cvt_w_kernel(
    const float* __restrict__ wq, const float* __restrict__ wk,
    const float* __restrict__ wv,
    ushort* __restrict__ Wh, ushort* __restrict__ Wl) {
  int lin8 = blockIdx.x * 256 + threadIdx.x;    // 98304 threads, 8 elems each
  int p = lin8 >> 15;
  int o = (lin8 & 32767) >> 6;
  int co = lin8 & 63;
  const float* Wsrc = (p == 0) ? wq : (p == 1) ? wk : wv;
  const float* src = &Wsrc[o * CC + co * 8];
  float4 f0 = *(const float4*)src;
  float4 f1 = *(const float4*)(src + 4);
  float f[8] = {f0.x, f0.y, f0.z, f0.w, f1.x, f1.y, f1.z, f1.w};
  ushort h8[8], l8[8];
#pragma unroll
  for (int j = 0; j < 8; ++j) {
    float sv = f[j] * 64.0f;
    ushort hi = f2h(sv);
    h8[j] = hi;
    l8[j] = f2h(sv - h2f(hi));
  }
  size_t dst = ((size_t)(p * CC + o)) * CC + co * 8;
  *(uint4*)&Wh[dst] = *(uint4*)h8;
  *(uint4*)&Wl[dst] = *(uint4*)l8;
}

// ---------------------------------------------------------------------------
// X transpose+convert: x[b][c][n] fp32 -> Xh[b][n][c] f16 hi only
// ---------------------------------------------------------------------------
__global__ __launch_bounds__(256) void cvt_x_kernel(
    const float* __restrict__ x, ushort* __restrict__ Xh) {
  int t = blockIdx.x * 256 + threadIdx.x;      // 524288 threads
  int nl = t & (NPIX - 1);
  int rest = t >> 10;
  int co = rest & 63;
  int b = rest >> 6;
  ushort h8[8];
#pragma unroll
  for (int j = 0; j < 8; ++j) {
    float v = x[(((size_t)(b * CC + co * 8 + j)) << 10) + nl];
    h8[j] = f2h(v);
  }
  size_t dst = (((size_t)(b * NPIX + nl)) << 9) + co * 8;
  *(uint4*)&Xh[dst] = *(uint4*)h8;
}

// ---------------------------------------------------------------------------
// Projection GEMM via f16 MFMA, 2-product compensation (W-side only).
// r16: q epilogue no longer emits a lo copy (attn S-phase is 1-product).
// ---------------------------------------------------------------------------
__global__ __launch_bounds__(256, 2) void proj_kernel(
    const ushort* __restrict__ Xh, const ushort* __restrict__ Wh,
    const ushort* __restrict__ Wl,
    const float* __restrict__ bq, const float* __restrict__ bk,
    const float* __restrict__ bv,
    ushort* __restrict__ KQh, ushort* __restrict__ Vb) {
  __shared__ __align__(16) ushort sW[128 * 128];   // 32KB
  __shared__ __align__(16) ushort sX[128 * 64];    // 16KB

  int tid = threadIdx.x;
  int lane = tid & 63;
  int w = tid >> 6;
  int col = lane & 31;
  int half = lane >> 5;
  int srow = lane >> 4;
  int sslot = lane & 15;

  int z = blockIdx.z;
  int b = z / 3, p = z % 3;
  const float* bias = (p == 0) ? bq : (p == 1) ? bk : bv;

  int n0 = blockIdx.x * 128;
  int o0 = blockIdx.y * 128;
  int wo = w >> 1;
  int wn = w & 1;

  f32x16 acc[2][2];
#pragma unroll
  for (int i = 0; i < 2; ++i)
#pragma unroll
    for (int j = 0; j < 2; ++j)
#pragma unroll
      for (int r = 0; r < 16; ++r) acc[i][j][r] = 0.f;

#pragma unroll 1
  for (int c0 = 0; c0 < CC; c0 += 64) {
#pragma unroll
    for (int i = 0; i < 8; ++i) {
      int rbase = (i * 4 + w) * 4;
      int row = rbase + srow;
      int j = sslot ^ (row & 15);
      int jc = j & 7;
      const ushort* src = (j < 8 || p == 2) ? Wh : Wl;
      size_t g = ((size_t)(p * CC + o0 + row)) * CC + c0 + jc * 8;
      gl16(src + g, (char*)sW + rbase * 256);
    }
#pragma unroll
    for (int i = 0; i < 4; ++i) {
      int rbase = i * 32 + w * 8;
      int row = rbase + (lane >> 3);
      int jc = (lane & 7) ^ (row & 7);
      size_t g = ((size_t)(b * NPIX + n0 + row)) * CC + c0 + jc * 8;
      gl16(Xh + g, (char*)sX + rbase * 128);
    }
    __syncthreads();

#pragma unroll
    for (int s = 0; s < 4; ++s) {
      if (p < 2) {
        f16x8 xa[2], wh_[2], wl_[2];
#pragma unroll
        for (int mt = 0; mt < 2; ++mt) {
          int row = wn * 64 + mt * 32 + col;
          int slot = ((s * 2 + half) ^ (row & 7)) << 4;
          xa[mt] = *(const f16x8*)((const char*)sX + row * 128 + slot);
        }
#pragma unroll
        for (int ct = 0; ct < 2; ++ct) {
          int row = wo * 64 + ct * 32 + col;
          int sh = ((s * 2 + half) ^ (row & 15)) << 4;
          int sl = ((8 + s * 2 + half) ^ (row & 15)) << 4;
          wh_[ct] = *(const f16x8*)((const char*)sW + row * 256 + sh);
          wl_[ct] = *(const f16x8*)((const char*)sW + row * 256 + sl);
        }
#pragma unroll
        for (int mt = 0; mt < 2; ++mt)
#pragma unroll
          for (int ct = 0; ct < 2; ++ct) {
            acc[mt][ct] = mfma32h(xa[mt], wh_[ct], acc[mt][ct]);
            acc[mt][ct] = mfma32h(xa[mt], wl_[ct], acc[mt][ct]);
          }
      } else {
        f16x8 wa[2], xb[2];
#pragma unroll
        for (int mt = 0; mt < 2; ++mt) {
          int row = wo * 64 + mt * 32 + col;
          int sh = ((s * 2 + half) ^ (row & 15)) << 4;
          wa[mt] = *(const f16x8*)((const char*)sW + row * 256 + sh);
        }
#pragma unroll
        for (int ct = 0; ct < 2; ++ct) {
          int row = wn * 64 + ct * 32 + col;
          int slot = ((s * 2 + half) ^ (row & 7)) << 4;
          xb[ct] = *(const f16x8*)((const char*)sX + row * 128 + slot);
        }
#pragma unroll
        for (int mt = 0; mt < 2; ++mt)
#pragma unroll
          for (int ct = 0; ct < 2; ++ct)
            acc[mt][ct] = mfma32h(wa[mt], xb[ct], acc[mt][ct]);
      }
    }
    __syncthreads();
  }

  const float INV64 = 0.015625f;
  if (p < 2) {
    float qscale = (p == 0) ? LOG2E : 1.0f;
#pragma unroll
    for (int ct = 0; ct < 2; ++ct) {
      int o = o0 + wo * 64 + ct * 32 + col;
      int bh = b * 8 + (o >> 6);
      int kk = ((p == 0) ? 64 : 0) + (o & 63);
      float bias_v = bias[o];
#pragma unroll
      for (int mt = 0; mt < 2; ++mt) {
        int nbase = n0 + wn * 64 + mt * 32;
#pragma unroll
        for (int r = 0; r < 16; ++r) {
          int n = nbase + (r & 3) + 8 * (r >> 2) + 4 * half;
          float v = (acc[mt][ct][r] * INV64 + bias_v) * qscale;
          size_t addr = (((size_t)bh << 10) + n) * 128 + kk;
          KQh[addr] = f2h(v);
        }
      }
    }
  } else {
#pragma unroll
    for (int ct = 0; ct < 2; ++ct) {
      int n = n0 + wn * 64 + ct * 32 + col;
#pragma unroll
      for (int mt = 0; mt < 2; ++mt) {
        int obase = o0 + wo * 64 + mt * 32;
#pragma unroll
        for (int r = 0; r < 16; ++r) {
          int o = obase + (r & 3) + 8 * (r >> 2) + 4 * half;
          int bh = b * 8 + (o >> 6);
          int d = o & 63;
          float v = acc[mt][ct][r] * INV64 + bias[o];
          Vb[(((size_t)(bh * 64 + d)) << 10) + n] = f2bf(v);
        }
      }
    }
  }
}

// ---------------------------------------------------------------------------
// Fused MFMA attention — r16: 1-product pure f16 S-phase (Q-lo dropped;
// K-lo drop already proven invisible in r7/r8 — symmetric roles). Double-
// buffered 64-key chunks, tree softmax reductions, 48KB LDS.
// ---------------------------------------------------------------------------
__global__ __launch_bounds__(256, 2) void attn_kernel(
    const ushort* __restrict__ KQh, const ushort* __restrict__ posH,
    const ushort* __restrict__ Vb, float* __restrict__ out) {
  __shared__ __align__(16) ushort sKh[2][64 * 128];   // 16KB each
  __shared__ __align__(16) ushort sV[2][64 * 64];     // 8KB each

  int tid = threadIdx.x;
  int lane = tid & 63;
  int w = tid >> 6;

  int bid = blockIdx.x;
  int wg = (bid & 7) * 64 + (bid >> 3);
  int bh = wg >> 3;
  int qb = wg & 7;
  int h = bh & 7;

  int col = lane & 31;
  int half = lane >> 5;
  int q0 = qb * 128 + w * 32;
  int q = q0 + col;

  // resident B-fragments (f16): [Q(n)*log2e | pos(n)], hi only
  uint4 bqh[8];
  {
    const ushort* rowQh = KQh + ((size_t)bh * NPIX + q) * 128;
#pragma unroll
    for (int s = 0; s < 4; ++s) {
      int off = 64 + s * 16 + half * 8;
      bqh[s] = *(const uint4*)(rowQh + off);
    }
    const ushort* rowPh = posH + ((size_t)(h * NPIX + q)) * 64;
#pragma unroll
    for (int s = 4; s < 8; ++s) {
      int off = (s - 4) * 16 + half * 8;
      bqh[s] = *(const uint4*)(rowPh + off);
    }
  }

  f32x16 oacc[2];
#pragma unroll
  for (int t = 0; t < 2; ++t)
#pragma unroll
    for (int r = 0; r < 16; ++r) oacc[t][r] = 0.f;
  float m_ = -1e30f, l_ = 0.f;

  int srow = lane >> 4;
  int sslot = lane & 15;

#define STAGE(bufi, k0)                                                      \
  {                                                                          \
    _Pragma("unroll")                                                        \
    for (int i = 0; i < 4; ++i) {                                            \
      int row = w * 16 + i * 4 + srow;                                       \
      size_t goff = ((size_t)bh * NPIX + (k0) + row) * 128 +                 \
                    ((sslot ^ (row & 15)) << 3);                             \
      gl16(KQh + goff, (char*)&sKh[bufi][0] + (w * 16 + i * 4) * 256);       \
    }                                                                        \
    _Pragma("unroll")                                                        \
    for (int i = 0; i < 2; ++i) {                                            \
      int d = w * 16 + i * 8 + (lane >> 3);                                  \
      int ks = (lane & 7) ^ (d & 7);                                         \
      size_t goff = ((size_t)(bh * 64 + d)) * NPIX + (k0) + (ks << 3);       \
      gl16(Vb + goff, (char*)&sV[bufi][0] + (w * 16 + i * 8) * 128);         \
    }                                                                        \
  }

  STAGE(0, 0);
  __syncthreads();

#pragma unroll 1
  for (int c = 0; c < 16; ++c) {
    int buf = c & 1;
    if (c < 15) STAGE(buf ^ 1, (c + 1) * 64);

    // ---- S phase: 2 key-tiles x 8 kk-steps x 1 f16 product ----
    f32x16 sa[2];
#pragma unroll
    for (int t = 0; t < 2; ++t)
#pragma unroll
      for (int r = 0; r < 16; ++r) sa[t][r] = 0.f;

    __builtin_amdgcn_s_setprio(1);
#pragma unroll
    for (int s = 0; s < 8; ++s) {
      U4H ubh;
      ubh.u = bqh[s];
#pragma unroll
      for (int t = 0; t < 2; ++t) {
        int row = t * 32 + col;
        int slot = ((s * 2 + half) ^ (row & 15)) << 4;
        const f16x8 ah = *(const f16x8*)((const char*)&sKh[buf][0] + row * 256 + slot);
        sa[t] = mfma32h(ah, ubh.v, sa[t]);
      }
    }
    __builtin_amdgcn_s_setprio(0);

    // ---- online softmax (exp2 domain), tree max, defer-max rescale ----
    float mxp[4];
#pragma unroll
    for (int j = 0; j < 4; ++j) {
      int ti = j >> 1;
      int b0 = (j & 1) * 8;
      float a = fmax3(sa[ti][b0 + 0], sa[ti][b0 + 1], sa[ti][b0 + 2]);
      float b1 = fmax3(sa[ti][b0 + 3], sa[ti][b0 + 4], sa[ti][b0 + 5]);
      float c1 = fmax3(sa[ti][b0 + 6], sa[ti][b0 + 7], a);
      mxp[j] = fmaxf(b1, c1);
    }
    float mx = fmaxf(fmax3(mxp[0], mxp[1], mxp[2]), mxp[3]);
    mx = fmaxf(mx, __shfl_xor(mx, 32));
    if (!__all(mx - m_ <= 11.54f)) {
      float mn = fmaxf(m_, mx);
      float sc = exp2raw(m_ - mn);
      l_ *= sc;
#pragma unroll
      for (int t = 0; t < 2; ++t)
#pragma unroll
        for (int r = 0; r < 16; ++r) oacc[t][r] *= sc;
      m_ = mn;
    }
#pragma unroll
    for (int t = 0; t < 2; ++t)
#pragma unroll
      for (int r = 0; r < 16; ++r) sa[t][r] = exp2raw(sa[t][r] - m_);
    float sp[8];
#pragma unroll
    for (int j = 0; j < 8; ++j) {
      int ti = j >> 2;
      int b0 = (j & 3) * 4;
      sp[j] = (sa[ti][b0 + 0] + sa[ti][b0 + 1]) + (sa[ti][b0 + 2] + sa[ti][b0 + 3]);
    }
    float ssum = ((sp[0] + sp[1]) + (sp[2] + sp[3])) + ((sp[4] + sp[5]) + (sp[6] + sp[7]));
    ssum += __shfl_xor(ssum, 32);
    l_ += ssum;

    // ---- PV (bf16), cvt_pk pack ----
#pragma unroll
    for (int t = 0; t < 2; ++t) {
      uint ua[4], ub[4], xa[4], xb[4];
#pragma unroll
      for (int g = 0; g < 4; ++g) {
        ua[g] = cvtpk(sa[t][4 * g + 0], sa[t][4 * g + 1]);
        ub[g] = cvtpk(sa[t][4 * g + 2], sa[t][4 * g + 3]);
      }
#pragma unroll
      for (int g = 0; g < 4; ++g) {
        xa[g] = __shfl_xor(ua[g], 32);
        xb[g] = __shfl_xor(ub[g], 32);
      }
      __builtin_amdgcn_s_setprio(1);
#pragma unroll
      for (int st = 0; st < 2; ++st) {
        int g = st * 2 + half;
        U4 pf;
        if (half == 0) {
          pf.u.x = ua[g]; pf.u.y = ub[g]; pf.u.z = xa[g]; pf.u.w = xb[g];
        } else {
          pf.u.x = xa[g]; pf.u.y = xb[g]; pf.u.z = ua[g]; pf.u.w = ub[g];
        }
#pragma unroll
        for (int dt = 0; dt < 2; ++dt) {
          int d = dt * 32 + col;
          int slot = ((t * 4 + st * 2 + half) ^ (d & 7)) << 4;
          const s16x8 vf = *(const s16x8*)((const char*)&sV[buf][0] + d * 128 + slot);
          oacc[dt] = mfma32(vf, pf.v, oacc[dt]);
        }
      }
      __builtin_amdgcn_s_setprio(0);
    }
    __syncthreads();
  }
#undef STAGE

  float inv = 1.0f / l_;
#pragma unroll
  for (int dt = 0; dt < 2; ++dt)
#pragma unroll
    for (int r = 0; r < 16; ++r) {
      int d = dt * 32 + (r & 3) + 8 * (r >> 2) + 4 * half;
      out[((size_t)(bh * 64 + d) << 10) + q] = oacc[dt][r] * inv;
    }
}

// ---------------------------------------------------------------------------
extern "C" void kernel_launch(void* const* d_in, const int* in_sizes, int n_in,
                              void* d_out, int out_size, void* d_ws, size_t ws_size,
                              hipStream_t stream) {
  const float* x     = (const float*)d_in[0];
  const float* wq    = (const float*)d_in[1];
  const float* bq    = (const float*)d_in[2];
  const float* wk    = (const float*)d_in[3];
  const float* bk    = (const float*)d_in[4];
  const float* wv    = (const float*)d_in[5];
  const float* bv    = (const float*)d_in[6];
  const float* rel_h = (const float*)d_in[7];
  const float* rel_w = (const float*)d_in[8];
  float* out = (float*)d_out;

  // ws (MB): KQh 16 | (free 16) | Vb 8 | posH 1 | (free 1) | Xh 8 | Wh 1.5 | Wl 1.5
  const size_t MB = 1024 * 1024;
  char* ws = (char*)d_ws;
  ushort* KQh  = (ushort*)(ws);
  ushort* Vb   = (ushort*)(ws + 32 * MB);
  ushort* posH = (ushort*)(ws + 40 * MB);
  ushort* Xh   = (ushort*)(ws + 42 * MB);
  ushort* Wh   = (ushort*)(ws + 50 * MB);
  ushort* Wl   = (ushort*)(ws + 50 * MB + 1572864);

  pos_kernel<<<dim3(256), dim3(256), 0, stream>>>(rel_h, rel_w, posH);
  cvt_w_kernel<<<dim3(384), dim3(256), 0, stream>>>(wq, wk, wv, Wh, Wl);
  cvt_x_kernel<<<dim3(2048), dim3(256), 0, stream>>>(x, Xh);
  proj_kernel<<<dim3(8, 4, 24), dim3(256), 0, stream>>>(
      Xh, Wh, Wl, bq, bk, bv, KQh, Vb);
  attn_kernel<<<dim3(512), dim3(256), 0, stream>>>(KQh, posH, Vb, out);
}